// Round 9
// baseline (465.326 us; speedup 1.0000x reference)
//
#include <hip/hip_runtime.h>
#include <stdint.h>

#define NN 100000
#define DF 128
#define NE 3200000
#define NELEM (NN * DF)          // 12,800,000
#define NBUCK 391                // row>>8 buckets (max row 99999>>8 = 390)
#define BCAP 12288               // bucket staging capacity (avg ~8184, +45 sigma)
#define BSTRIDE 16               // bcnt padding: one counter per 64B line
#define EPB 4096                 // edges per binfill block (16 per thread)
#define NBINBLK ((NE + EPB - 1) / EPB)   // 782
#define OVF_CAP 65536

// ---------------- Threefry-2x32 (JAX-exact, partitionable, bits = x0^x1) ----
__host__ __device__ __forceinline__ void tf2x32(uint32_t& x0, uint32_t& x1,
                                                uint32_t k0, uint32_t k1) {
  uint32_t ks2 = k0 ^ k1 ^ 0x1BD11BDAu;
  x0 += k0; x1 += k1;
#define TF_RND(r) { x0 += x1; x1 = (x1 << (r)) | (x1 >> (32 - (r))); x1 ^= x0; }
  TF_RND(13) TF_RND(15) TF_RND(26) TF_RND(6)
  x0 += k1;  x1 += ks2 + 1u;
  TF_RND(17) TF_RND(29) TF_RND(16) TF_RND(24)
  x0 += ks2; x1 += k0 + 2u;
  TF_RND(13) TF_RND(15) TF_RND(26) TF_RND(6)
  x0 += k0;  x1 += k1 + 3u;
  TF_RND(17) TF_RND(29) TF_RND(16) TF_RND(24)
  x0 += k1;  x1 += ks2 + 4u;
  TF_RND(13) TF_RND(15) TF_RND(26) TF_RND(6)
  x0 += ks2; x1 += k0 + 5u;
#undef TF_RND
}

__device__ __forceinline__ bool keep_elem(uint32_t kA, uint32_t kB, uint32_t idx) {
  uint32_t x0 = 0u, x1 = idx;          // counter = (hi=0, lo=i)
  tf2x32(x0, x1, kA, kB);
  uint32_t bits = x0 ^ x1;             // partitionable combine (verified r2)
  float u = __uint_as_float((bits >> 9) | 0x3f800000u) - 1.0f;
  return u < 0.9f;
}

// ---------------- bf16 helpers (internal compression only) ----------------
__device__ __forceinline__ uint16_t f2bf(float f) {  // round-to-nearest-even
  uint32_t x = __float_as_uint(f);
  uint32_t r = x + 0x7fffu + ((x >> 16) & 1u);
  return (uint16_t)(r >> 16);
}

// pack: row:17 (bits 47..63) | col:17 (bits 30..46) | (val_bits>>2):30 (bits 0..29)
__device__ __forceinline__ uint64_t pack_edge(int row, int col, float val) {
  return ((uint64_t)(uint32_t)row << 47) | ((uint64_t)(uint32_t)col << 30) |
         (uint64_t)(__float_as_uint(val) >> 2);
}

// CSR record: col:17 (bits 15..31) | val:15 fixed-point m/32768 (bits 0..14)
__device__ __forceinline__ uint32_t pack_csr(int col, float v) {
  int m = (int)(v * 32768.0f + 0.5f);
  if (m > 32767) m = 32767;
  return ((uint32_t)col << 15) | (uint32_t)m;
}

// ============ phase 1: block-local LDS binning, chunked claims ============
__global__ __launch_bounds__(256) void binfill2_kernel(
    const int* __restrict__ rows, const int* __restrict__ cols,
    const float* __restrict__ vals,
    int* __restrict__ bcnt,            // [NBUCK*BSTRIDE], line-padded
    int* __restrict__ ovf_cnt, int* __restrict__ row_cnt_ovf,
    uint64_t* __restrict__ staging, uint64_t* __restrict__ ovf) {
  __shared__ int lcnt[NBUCK];
  __shared__ int lcur[NBUCK];
  int t = threadIdx.x;
  for (int i = t; i < NBUCK; i += 256) lcnt[i] = 0;
  __syncthreads();

  int base = blockIdx.x * EPB;
  int rr[16];
#pragma unroll
  for (int k = 0; k < 16; ++k) {
    int e = base + k * 256 + t;
    rr[k] = (e < NE) ? rows[e] : -1;
    if (rr[k] >= 0) atomicAdd(&lcnt[rr[k] >> 8], 1);
  }
  __syncthreads();
  for (int i = t; i < NBUCK; i += 256)
    lcur[i] = atomicAdd(&bcnt[i * BSTRIDE], lcnt[i]);
  __syncthreads();
#pragma unroll
  for (int k = 0; k < 16; ++k) {
    if (rr[k] < 0) continue;
    int e = base + k * 256 + t;
    int row = rr[k];
    int b = row >> 8;
    uint64_t packed = pack_edge(row, cols[e], vals[e]);
    int slot = atomicAdd(&lcur[b], 1);
    if (slot < BCAP) {
      staging[(size_t)b * BCAP + slot] = packed;
    } else {
      int o = atomicAdd(ovf_cnt, 1);
      if (o < OVF_CAP) ovf[o] = packed;
      atomicAdd(&row_cnt_ovf[row], 1);
    }
  }
}

// ============ bucket-offset scan (391 values, 1 block) ============
__global__ __launch_bounds__(512) void scan_bsums_kernel(const int* __restrict__ bcnt,
                                                         int* __restrict__ boff) {
  __shared__ int lds[512];
  int tid = threadIdx.x;
  int v = (tid < NBUCK) ? bcnt[tid * BSTRIDE] : 0;
  lds[tid] = v;
  __syncthreads();
#pragma unroll
  for (int off = 1; off < 512; off <<= 1) {
    int add = (tid >= off) ? lds[tid - off] : 0;
    __syncthreads();
    lds[tid] += add;
    __syncthreads();
  }
  if (tid < NBUCK) boff[tid] = lds[tid] - v;   // exclusive
}

// ============ phase 2: bucket -> CSR (block b owns rows [b*256, b*256+256)) ====
__global__ __launch_bounds__(256) void scatter_csr2_kernel(
    const int* __restrict__ bcnt, const int* __restrict__ boff,
    const int* __restrict__ row_cnt_ovf,
    const uint64_t* __restrict__ staging,
    int* __restrict__ row_ptr, int* __restrict__ row_fill,
    uint32_t* __restrict__ csr) {
  __shared__ int scnt[256];      // staged count per local row
  __shared__ int lds[256];       // scan workspace
  __shared__ int lcur[256];      // write cursors
  int b = blockIdx.x;
  int t = threadIdx.x;
  int g = b * 256 + t;           // global row
  int n_tot = bcnt[b * BSTRIDE];
  int n_stg = min(n_tot, BCAP);
  const uint64_t* src = staging + (size_t)b * BCAP;

  scnt[t] = 0;
  __syncthreads();
  for (int i = t; i < n_stg; i += 256)
    atomicAdd(&scnt[(int)(src[i] >> 47) & 255], 1);
  __syncthreads();
  int ovfc = (g < NN) ? row_cnt_ovf[g] : 0;
  int v = scnt[t] + ovfc;
  lds[t] = v;
  __syncthreads();
#pragma unroll
  for (int off = 1; off < 256; off <<= 1) {
    int add = (t >= off) ? lds[t - off] : 0;
    __syncthreads();
    lds[t] += add;
    __syncthreads();
  }
  int excl = lds[t] - v;
  int bo = boff[b];
  if (g <= NN) row_ptr[g] = bo + excl;
  if (g < NN) row_fill[g] = bo + excl + scnt[t];
  lcur[t] = excl;
  __syncthreads();
  for (int i = t; i < n_stg; i += 256) {
    uint64_t p = src[i];
    int rl = (int)(p >> 47) & 255;
    int col = (int)((p >> 30) & 0x1FFFFu);
    float vv = __uint_as_float(((uint32_t)p & 0x3FFFFFFFu) << 2);
    int pos = bo + atomicAdd(&lcur[rl], 1);
    csr[pos] = pack_csr(col, vv);
  }
}

// ============ overflow drain (normally 0 edges) ============
__global__ __launch_bounds__(256) void ovf_drain_kernel(
    const int* __restrict__ ovf_cnt, const uint64_t* __restrict__ ovf,
    int* __restrict__ row_fill, uint32_t* __restrict__ csr) {
  int n = min(*ovf_cnt, OVF_CAP);
  for (int i = threadIdx.x; i < n; i += 256) {
    uint64_t p = ovf[i];
    int row = (int)(p >> 47);
    int col = (int)((p >> 30) & 0x1FFFFu);
    float vv = __uint_as_float(((uint32_t)p & 0x3FFFFFFFu) << 2);
    int pos = atomicAdd(&row_fill[row], 1);
    csr[pos] = pack_csr(col, vv);
  }
}

// ---------------- f32 -> bf16 table convert ----------------
__global__ __launch_bounds__(256) void convert_kernel(const float4* __restrict__ src,
                                                      ushort4* __restrict__ dst) {
  int i = blockIdx.x * 256 + threadIdx.x;
  if (i < NELEM / 4) {
    float4 v = src[i];
    dst[i] = make_ushort4(f2bf(v.x), f2bf(v.y), f2bf(v.z), f2bf(v.w));
  }
}

// ============== fused SpMM + residual + dropout — feature-split, row-paired ====
// PASS selects features [PASS*64, PASS*64+64). One wave64 = 2 rows:
// lanes 0..31 -> row 2*pr (edge stream A), lanes 32..63 -> row 2*pr+1 (stream B).
// CSR streams stay scalar (s_load, wave-uniform); one 256B gather instruction
// serves 2 edges' half-rows (12.8 MB working set per pass -> better L2 hit).
// MODE 0/1: write h half (bf16). MODE 2: out = (q + h1 + h2 + h3) * 0.25.
template <int MODE, int PASS>
__global__ __launch_bounds__(256) void spmm_half_kernel(
    const int* __restrict__ row_ptr,
    const uint32_t* __restrict__ csr,   // col:17 | val:15 fixed point
    const uint32_t* __restrict__ xb,    // bf16x2 gather table (layer input)
    const uint32_t* __restrict__ qb,    // bf16x2 q (MODE 2)
    const uint32_t* __restrict__ h1b,   // bf16x2 h1 (MODE 2)
    uint32_t* __restrict__ hb_out,      // bf16x2 h out (MODE 0/1)
    float2* __restrict__ outv,          // final output (MODE 2)
    uint32_t kA, uint32_t kB) {
  int pr = __builtin_amdgcn_readfirstlane(blockIdx.x * 4 + (threadIdx.x >> 6));
  int rA = pr * 2;                     // wave-uniform; grid exact (NN/2 % 4 == 0)
  int lane = threadIdx.x & 63;
  int l = lane & 31;
  int half = lane >> 5;

  int begA = row_ptr[rA];              // uniform -> s_load
  int endA = row_ptr[rA + 1];
  int endB = row_ptr[rA + 2];
  int lenA = endA - begA, lenB = endB - endA;
  const uint32_t* csrA = csr + begA;
  const uint32_t* csrB = csr + endA;
  int ml = lenA > lenB ? lenA : lenB;

  const char* xbase = (const char*)xb;
  uint32_t loff = (uint32_t)(PASS * 128 + (l << 2));  // byte off within row

  float s0 = 0.f, s1 = 0.f;
  int j = 0, ml8 = ml & ~7;
  for (; j < ml8; j += 8) {
    uint32_t cw[8];
#pragma unroll
    for (int u = 0; u < 8; ++u) {
      // bounded overread (<=8 dwords past row end, inside workspace); masked
      uint32_t a = csrA[j + u]; a = (j + u < lenA) ? a : 0u;   // s_cselect
      uint32_t b = csrB[j + u]; b = (j + u < lenB) ? b : 0u;
      cw[u] = half ? b : a;                                    // v_cndmask
    }
    uint32_t ta[8];
#pragma unroll
    for (int u = 0; u < 8; ++u) {
      uint32_t off = ((cw[u] >> 15) << 8) + loff;   // row*256B + feature off
      ta[u] = *(const uint32_t*)(xbase + off);      // 2 edges per instruction
    }
#pragma unroll
    for (int u = 0; u < 8; ++u) {
      float v = (float)(cw[u] & 0x7FFFu);           // scale deferred
      s0 += v * __uint_as_float(ta[u] << 16);
      s1 += v * __uint_as_float(ta[u] & 0xFFFF0000u);
    }
  }
  for (; j < ml; ++j) {
    uint32_t a = csrA[j]; a = (j < lenA) ? a : 0u;
    uint32_t b = csrB[j]; b = (j < lenB) ? b : 0u;
    uint32_t cw = half ? b : a;
    uint32_t t = *(const uint32_t*)(xbase + (((cw >> 15) << 8) + loff));
    float v = (float)(cw & 0x7FFFu);
    s0 += v * __uint_as_float(t << 16);
    s1 += v * __uint_as_float(t & 0xFFFF0000u);
  }
  s0 *= (1.0f / 32768.0f);
  s1 *= (1.0f / 32768.0f);

  int r = rA + half;                    // per-lane row
  int oi = r * 64 + PASS * 32 + l;      // dword index into bf16x2 arrays
  uint32_t pw = xb[oi];                 // own half-row = residual source
  float p0 = __uint_as_float(pw << 16);
  float p1 = __uint_as_float(pw & 0xFFFF0000u);

  uint32_t base = (uint32_t)r * 128u + (uint32_t)(PASS * 64) + (uint32_t)(l << 1);
  float t0 = s0 + p0, t1 = s1 + p1;
  float h0 = keep_elem(kA, kB, base)      ? t0 * (1.0f / 0.9f) : 0.0f;
  float h1 = keep_elem(kA, kB, base + 1u) ? t1 * (1.0f / 0.9f) : 0.0f;

  if (MODE < 2) {
    hb_out[oi] = (uint32_t)f2bf(h0) | ((uint32_t)f2bf(h1) << 16);
  } else {
    uint32_t qw = qb[oi];
    uint32_t hw = h1b[oi];
    float q0 = __uint_as_float(qw << 16), q1 = __uint_as_float(qw & 0xFFFF0000u);
    float a0 = __uint_as_float(hw << 16), a1 = __uint_as_float(hw & 0xFFFF0000u);
    // out = (q + h1 + h2 + h3) / 4 ; here p = h2 (own row), h = h3
    outv[oi] = make_float2((q0 + a0 + p0 + h0) * 0.25f,
                           (q1 + a1 + p1 + h1) * 0.25f);
  }
}

// ======================= launch =======================
extern "C" void kernel_launch(void* const* d_in, const int* in_sizes, int n_in,
                              void* d_out, int out_size, void* d_ws, size_t ws_size,
                              hipStream_t stream) {
  const float* q   = (const float*)d_in[0];
  const int* rows  = (const int*)d_in[1];
  const int* cols  = (const int*)d_in[2];
  const float* vls = (const float*)d_in[3];
  float* out = (float*)d_out;

  // layer keys: fold_in(key(42), layer) = threefry2x32((0,42),(0,layer))
  uint32_t kA[3], kB[3];
  for (int l = 0; l < 3; ++l) {
    uint32_t x0 = 0u, x1 = (uint32_t)l;
    tf2x32(x0, x1, 0u, 42u);
    kA[l] = x0; kB[l] = x1;
  }

  // ---- workspace layout (~92 MB) ----
  uint16_t* xb_q = (uint16_t*)d_ws;               // NELEM bf16 (25.6 MB)
  uint16_t* hb1  = xb_q + NELEM;                  // NELEM bf16 (25.6 MB)
  uint16_t* hb2  = hb1 + NELEM;                   // NELEM bf16 (25.6 MB)
  uint64_t* staging = (uint64_t*)hb1;             // 38.4 MB, aliases hb1+hb2 (dead before spmm0)
  uint32_t* csr  = (uint32_t*)(hb2 + NELEM);      // NE u32 (12.8 MB)
  int* row_ptr   = (int*)(csr + NE);              // NN+1
  int* boff      = row_ptr + NN + 1;              // NBUCK
  int* row_fill  = boff + NBUCK;                  // NN
  int* row_cnt_ovf = row_fill + NN;               // NN      -- zero region start
  int* bcnt      = row_cnt_ovf + NN;              // NBUCK*BSTRIDE
  int* ovf_cnt   = bcnt + NBUCK * BSTRIDE;        // 1       -- zero region end
  uint64_t* ovf  = (uint64_t*)(((uintptr_t)(ovf_cnt + 1) + 7) & ~(uintptr_t)7);

  dim3 blk(256);

  hipMemsetAsync(row_cnt_ovf, 0, (size_t)(NN + NBUCK * BSTRIDE + 1) * 4, stream);
  convert_kernel<<<NELEM / 4 / 256, blk, 0, stream>>>((const float4*)q, (ushort4*)xb_q);
  binfill2_kernel<<<NBINBLK, blk, 0, stream>>>(
      rows, cols, vls, bcnt, ovf_cnt, row_cnt_ovf, staging, ovf);
  scan_bsums_kernel<<<1, 512, 0, stream>>>(bcnt, boff);
  scatter_csr2_kernel<<<NBUCK, blk, 0, stream>>>(
      bcnt, boff, row_cnt_ovf, staging, row_ptr, row_fill, csr);
  ovf_drain_kernel<<<1, blk, 0, stream>>>(ovf_cnt, ovf, row_fill, csr);

  const int grid = NN / 2 / 4;   // 2 rows per wave, 4 waves per block = 12500
  const uint32_t* xq = (const uint32_t*)xb_q;
  uint32_t* h1 = (uint32_t*)hb1;
  uint32_t* h2 = (uint32_t*)hb2;

  spmm_half_kernel<0, 0><<<grid, blk, 0, stream>>>(
      row_ptr, csr, xq, nullptr, nullptr, h1, nullptr, kA[0], kB[0]);
  spmm_half_kernel<0, 1><<<grid, blk, 0, stream>>>(
      row_ptr, csr, xq, nullptr, nullptr, h1, nullptr, kA[0], kB[0]);
  spmm_half_kernel<1, 0><<<grid, blk, 0, stream>>>(
      row_ptr, csr, h1, nullptr, nullptr, h2, nullptr, kA[1], kB[1]);
  spmm_half_kernel<1, 1><<<grid, blk, 0, stream>>>(
      row_ptr, csr, h1, nullptr, nullptr, h2, nullptr, kA[1], kB[1]);
  spmm_half_kernel<2, 0><<<grid, blk, 0, stream>>>(
      row_ptr, csr, h2, xq, h1, nullptr, (float2*)out, kA[2], kB[2]);
  spmm_half_kernel<2, 1><<<grid, blk, 0, stream>>>(
      row_ptr, csr, h2, xq, h1, nullptr, (float2*)out, kA[2], kB[2]);
}

// Round 10
// 421.867 us; speedup vs baseline: 1.1030x; 1.1030x over previous
//
#include <hip/hip_runtime.h>
#include <stdint.h>

#define NN 100000
#define DF 128
#define NE 3200000
#define NELEM (NN * DF)          // 12,800,000
#define NBUCK 391                // row>>8 buckets (max row 99999>>8 = 390)
#define BCAP 12288               // bucket staging capacity (avg ~8184, +45 sigma)
#define BSTRIDE 16               // bcnt padding: one counter per 64B line
#define EPB 8192                 // edges per binfill block (16 per thread, 512 thr)
#define NBINBLK ((NE + EPB - 1) / EPB)   // 391
#define OVF_CAP 65536

// ---------------- Threefry-2x32 (JAX-exact, partitionable, bits = x0^x1) ----
__host__ __device__ __forceinline__ void tf2x32(uint32_t& x0, uint32_t& x1,
                                                uint32_t k0, uint32_t k1) {
  uint32_t ks2 = k0 ^ k1 ^ 0x1BD11BDAu;
  x0 += k0; x1 += k1;
#define TF_RND(r) { x0 += x1; x1 = (x1 << (r)) | (x1 >> (32 - (r))); x1 ^= x0; }
  TF_RND(13) TF_RND(15) TF_RND(26) TF_RND(6)
  x0 += k1;  x1 += ks2 + 1u;
  TF_RND(17) TF_RND(29) TF_RND(16) TF_RND(24)
  x0 += ks2; x1 += k0 + 2u;
  TF_RND(13) TF_RND(15) TF_RND(26) TF_RND(6)
  x0 += k0;  x1 += k1 + 3u;
  TF_RND(17) TF_RND(29) TF_RND(16) TF_RND(24)
  x0 += k1;  x1 += ks2 + 4u;
  TF_RND(13) TF_RND(15) TF_RND(26) TF_RND(6)
  x0 += ks2; x1 += k0 + 5u;
#undef TF_RND
}

__device__ __forceinline__ bool keep_elem(uint32_t kA, uint32_t kB, uint32_t idx) {
  uint32_t x0 = 0u, x1 = idx;          // counter = (hi=0, lo=i)
  tf2x32(x0, x1, kA, kB);
  uint32_t bits = x0 ^ x1;             // partitionable combine (verified r2)
  float u = __uint_as_float((bits >> 9) | 0x3f800000u) - 1.0f;
  return u < 0.9f;
}

// ---------------- bf16 helpers (internal compression only) ----------------
__device__ __forceinline__ uint16_t f2bf(float f) {  // round-to-nearest-even
  uint32_t x = __float_as_uint(f);
  uint32_t r = x + 0x7fffu + ((x >> 16) & 1u);
  return (uint16_t)(r >> 16);
}

// pack: row:17 (bits 47..63) | col:17 (bits 30..46) | (val_bits>>2):30 (bits 0..29)
__device__ __forceinline__ uint64_t pack_edge(int row, int col, float val) {
  return ((uint64_t)(uint32_t)row << 47) | ((uint64_t)(uint32_t)col << 30) |
         (uint64_t)(__float_as_uint(val) >> 2);
}

// CSR record: col:17 (bits 15..31) | val:15 fixed-point m/32768 (bits 0..14)
__device__ __forceinline__ uint32_t pack_csr(int col, float v) {
  int m = (int)(v * 32768.0f + 0.5f);
  if (m > 32767) m = 32767;
  return ((uint32_t)col << 15) | (uint32_t)m;
}

// ============ phase 1: block-local LDS binning, chunked claims ============
// 512 threads, 8192 edges/block -> ~21-edge (168B) chunks per bucket: most
// staging lines written whole by one CU (write-amp ~1.4x vs 4x at EPB=4096).
__global__ __launch_bounds__(512) void binfill2_kernel(
    const int* __restrict__ rows, const int* __restrict__ cols,
    const float* __restrict__ vals,
    int* __restrict__ bcnt,            // [NBUCK*BSTRIDE], line-padded
    int* __restrict__ ovf_cnt, int* __restrict__ row_cnt_ovf,
    uint64_t* __restrict__ staging, uint64_t* __restrict__ ovf) {
  __shared__ int lcnt[NBUCK];
  __shared__ int lcur[NBUCK];
  int t = threadIdx.x;
  for (int i = t; i < NBUCK; i += 512) lcnt[i] = 0;
  __syncthreads();

  int base = blockIdx.x * EPB;
  int rr[16];
#pragma unroll
  for (int k = 0; k < 16; ++k) {
    int e = base + k * 512 + t;
    rr[k] = (e < NE) ? rows[e] : -1;
    if (rr[k] >= 0) atomicAdd(&lcnt[rr[k] >> 8], 1);
  }
  __syncthreads();
  for (int i = t; i < NBUCK; i += 512)
    lcur[i] = atomicAdd(&bcnt[i * BSTRIDE], lcnt[i]);
  __syncthreads();
#pragma unroll
  for (int k = 0; k < 16; ++k) {
    if (rr[k] < 0) continue;
    int e = base + k * 512 + t;
    int row = rr[k];
    int b = row >> 8;
    uint64_t packed = pack_edge(row, cols[e], vals[e]);
    int slot = atomicAdd(&lcur[b], 1);
    if (slot < BCAP) {
      staging[(size_t)b * BCAP + slot] = packed;
    } else {
      int o = atomicAdd(ovf_cnt, 1);
      if (o < OVF_CAP) ovf[o] = packed;
      atomicAdd(&row_cnt_ovf[row], 1);
    }
  }
}

// ============ bucket-offset scan (391 values, 1 block) ============
__global__ __launch_bounds__(512) void scan_bsums_kernel(const int* __restrict__ bcnt,
                                                         int* __restrict__ boff) {
  __shared__ int lds[512];
  int tid = threadIdx.x;
  int v = (tid < NBUCK) ? bcnt[tid * BSTRIDE] : 0;
  lds[tid] = v;
  __syncthreads();
#pragma unroll
  for (int off = 1; off < 512; off <<= 1) {
    int add = (tid >= off) ? lds[tid - off] : 0;
    __syncthreads();
    lds[tid] += add;
    __syncthreads();
  }
  if (tid < NBUCK) boff[tid] = lds[tid] - v;   // exclusive
}

// ============ phase 2: bucket -> CSR (block b owns rows [b*256, b*256+256)) ====
__global__ __launch_bounds__(256) void scatter_csr2_kernel(
    const int* __restrict__ bcnt, const int* __restrict__ boff,
    const int* __restrict__ row_cnt_ovf,
    const uint64_t* __restrict__ staging,
    int* __restrict__ row_ptr, int* __restrict__ row_fill,
    uint32_t* __restrict__ csr) {
  __shared__ int scnt[256];      // staged count per local row
  __shared__ int lds[256];       // scan workspace
  __shared__ int lcur[256];      // write cursors
  int b = blockIdx.x;
  int t = threadIdx.x;
  int g = b * 256 + t;           // global row
  int n_tot = bcnt[b * BSTRIDE];
  int n_stg = min(n_tot, BCAP);
  const uint64_t* src = staging + (size_t)b * BCAP;

  scnt[t] = 0;
  __syncthreads();
  for (int i = t; i < n_stg; i += 256)
    atomicAdd(&scnt[(int)(src[i] >> 47) & 255], 1);
  __syncthreads();
  int ovfc = (g < NN) ? row_cnt_ovf[g] : 0;
  int v = scnt[t] + ovfc;
  lds[t] = v;
  __syncthreads();
#pragma unroll
  for (int off = 1; off < 256; off <<= 1) {
    int add = (t >= off) ? lds[t - off] : 0;
    __syncthreads();
    lds[t] += add;
    __syncthreads();
  }
  int excl = lds[t] - v;
  int bo = boff[b];
  if (g <= NN) row_ptr[g] = bo + excl;
  if (g < NN) row_fill[g] = bo + excl + scnt[t];
  lcur[t] = excl;
  __syncthreads();
  for (int i = t; i < n_stg; i += 256) {
    uint64_t p = src[i];
    int rl = (int)(p >> 47) & 255;
    int col = (int)((p >> 30) & 0x1FFFFu);
    float vv = __uint_as_float(((uint32_t)p & 0x3FFFFFFFu) << 2);
    int pos = bo + atomicAdd(&lcur[rl], 1);
    csr[pos] = pack_csr(col, vv);
  }
}

// ============ overflow drain (normally 0 edges) ============
__global__ __launch_bounds__(256) void ovf_drain_kernel(
    const int* __restrict__ ovf_cnt, const uint64_t* __restrict__ ovf,
    int* __restrict__ row_fill, uint32_t* __restrict__ csr) {
  int n = min(*ovf_cnt, OVF_CAP);
  for (int i = threadIdx.x; i < n; i += 256) {
    uint64_t p = ovf[i];
    int row = (int)(p >> 47);
    int col = (int)((p >> 30) & 0x1FFFFu);
    float vv = __uint_as_float(((uint32_t)p & 0x3FFFFFFFu) << 2);
    int pos = atomicAdd(&row_fill[row], 1);
    csr[pos] = pack_csr(col, vv);
  }
}

// ---------------- f32 -> bf16 table convert ----------------
__global__ __launch_bounds__(256) void convert_kernel(const float4* __restrict__ src,
                                                      ushort4* __restrict__ dst) {
  int i = blockIdx.x * 256 + threadIdx.x;
  if (i < NELEM / 4) {
    float4 v = src[i];
    dst[i] = make_ushort4(f2bf(v.x), f2bf(v.y), f2bf(v.z), f2bf(v.w));
  }
}

// ============== fused SpMM + residual + dropout (r8 version, verified) ==============
// One wave64 per row; lane owns one bf16x2 dword. Row wave-uniform
// (readfirstlane) => CSR stream s_load'ed, gathers saddr-form.
// MODE 0/1: h = dropout(spmm(x) + x_own); write h (bf16). No acc buffer.
// MODE 2:   h3 in-register; out = (q + h1 + h2 + h3) * 0.25 (f32).
template <int MODE>
__global__ __launch_bounds__(256) void spmm_layer_kernel(
    const int* __restrict__ row_ptr,
    const uint32_t* __restrict__ csr,   // col:17 | val:15 fixed point
    const uint32_t* __restrict__ xb,    // bf16x2 gather table (layer input)
    const uint32_t* __restrict__ qb,    // bf16x2 q (MODE 2)
    const uint32_t* __restrict__ h1b,   // bf16x2 h1 (MODE 2)
    uint32_t* __restrict__ hb_out,      // bf16x2 h out (MODE 0/1)
    float2* __restrict__ outv,          // final output (MODE 2)
    uint32_t kA, uint32_t kB) {
  int r = __builtin_amdgcn_readfirstlane(blockIdx.x * 4 + (threadIdx.x >> 6));
  if (r >= NN) return;                  // grid exact (NN % 4 == 0)
  int lane = threadIdx.x & 63;
  int beg = row_ptr[r], end = row_ptr[r + 1];   // uniform -> scalar loads

  float s0a = 0.f, s1a = 0.f, s0b = 0.f, s1b = 0.f;
  int j = beg;
  int n8 = beg + ((end - beg) & ~7);
  for (; j < n8; j += 8) {              // 8 gathers in flight
    uint32_t cv[8];
#pragma unroll
    for (int u = 0; u < 8; ++u) cv[u] = csr[j + u];   // uniform -> s_load
    uint32_t t[8];
#pragma unroll
    for (int u = 0; u < 8; ++u) {
      const uint32_t* p = xb + (size_t)(cv[u] >> 15) * 64;  // SGPR base
      t[u] = p[lane];                                       // saddr gather
    }
#pragma unroll
    for (int u = 0; u < 8; ++u) {
      float v = (float)(cv[u] & 0x7FFFu) * (1.0f / 32768.0f);
      float lo = __uint_as_float(t[u] << 16);
      float hi = __uint_as_float(t[u] & 0xFFFF0000u);
      if (u & 1) { s0b += v * lo; s1b += v * hi; }
      else       { s0a += v * lo; s1a += v * hi; }
    }
  }
  for (; j < end; ++j) {
    uint32_t cv = csr[j];
    float v = (float)(cv & 0x7FFFu) * (1.0f / 32768.0f);
    const uint32_t* p = xb + (size_t)(cv >> 15) * 64;
    uint32_t t = p[lane];
    s0a += v * __uint_as_float(t << 16);
    s1a += v * __uint_as_float(t & 0xFFFF0000u);
  }
  float s0 = s0a + s0b, s1 = s1a + s1b;

  int oi = r * 64 + lane;
  uint32_t pw = xb[oi];                 // own row = residual source
  float p0 = __uint_as_float(pw << 16);
  float p1 = __uint_as_float(pw & 0xFFFF0000u);

  uint32_t base = (uint32_t)r * 128u + (uint32_t)lane * 2u;
  float t0 = s0 + p0, t1 = s1 + p1;
  float h0 = keep_elem(kA, kB, base)      ? t0 * (1.0f / 0.9f) : 0.0f;
  float h1 = keep_elem(kA, kB, base + 1u) ? t1 * (1.0f / 0.9f) : 0.0f;

  if (MODE < 2) {
    hb_out[oi] = (uint32_t)f2bf(h0) | ((uint32_t)f2bf(h1) << 16);
  } else {
    uint32_t qw = qb[oi];
    uint32_t hw = h1b[oi];
    float q0 = __uint_as_float(qw << 16), q1 = __uint_as_float(qw & 0xFFFF0000u);
    float a0 = __uint_as_float(hw << 16), a1 = __uint_as_float(hw & 0xFFFF0000u);
    // out = (q + h1 + h2 + h3) / 4 ; here p = h2 (own row), h = h3
    outv[oi] = make_float2((q0 + a0 + p0 + h0) * 0.25f,
                           (q1 + a1 + p1 + h1) * 0.25f);
  }
}

// ======================= launch =======================
extern "C" void kernel_launch(void* const* d_in, const int* in_sizes, int n_in,
                              void* d_out, int out_size, void* d_ws, size_t ws_size,
                              hipStream_t stream) {
  const float* q   = (const float*)d_in[0];
  const int* rows  = (const int*)d_in[1];
  const int* cols  = (const int*)d_in[2];
  const float* vls = (const float*)d_in[3];
  float* out = (float*)d_out;

  // layer keys: fold_in(key(42), layer) = threefry2x32((0,42),(0,layer))
  uint32_t kA[3], kB[3];
  for (int l = 0; l < 3; ++l) {
    uint32_t x0 = 0u, x1 = (uint32_t)l;
    tf2x32(x0, x1, 0u, 42u);
    kA[l] = x0; kB[l] = x1;
  }

  // ---- workspace layout (~92 MB) ----
  uint16_t* xb_q = (uint16_t*)d_ws;               // NELEM bf16 (25.6 MB)
  uint16_t* hb1  = xb_q + NELEM;                  // NELEM bf16 (25.6 MB)
  uint16_t* hb2  = hb1 + NELEM;                   // NELEM bf16 (25.6 MB)
  uint64_t* staging = (uint64_t*)hb1;             // 38.4 MB, aliases hb1+hb2 (dead before spmm0)
  uint32_t* csr  = (uint32_t*)(hb2 + NELEM);      // NE u32 (12.8 MB)
  int* row_ptr   = (int*)(csr + NE);              // NN+1
  int* boff      = row_ptr + NN + 1;              // NBUCK
  int* row_fill  = boff + NBUCK;                  // NN
  int* row_cnt_ovf = row_fill + NN;               // NN      -- zero region start
  int* bcnt      = row_cnt_ovf + NN;              // NBUCK*BSTRIDE
  int* ovf_cnt   = bcnt + NBUCK * BSTRIDE;        // 1       -- zero region end
  uint64_t* ovf  = (uint64_t*)(((uintptr_t)(ovf_cnt + 1) + 7) & ~(uintptr_t)7);

  dim3 blk(256);

  hipMemsetAsync(row_cnt_ovf, 0, (size_t)(NN + NBUCK * BSTRIDE + 1) * 4, stream);
  convert_kernel<<<NELEM / 4 / 256, blk, 0, stream>>>((const float4*)q, (ushort4*)xb_q);
  binfill2_kernel<<<NBINBLK, dim3(512), 0, stream>>>(
      rows, cols, vls, bcnt, ovf_cnt, row_cnt_ovf, staging, ovf);
  scan_bsums_kernel<<<1, 512, 0, stream>>>(bcnt, boff);
  scatter_csr2_kernel<<<NBUCK, blk, 0, stream>>>(
      bcnt, boff, row_cnt_ovf, staging, row_ptr, row_fill, csr);
  ovf_drain_kernel<<<1, blk, 0, stream>>>(ovf_cnt, ovf, row_fill, csr);

  const int grid = NN / 4;   // one wave64 per row, 4 rows per block
  spmm_layer_kernel<0><<<grid, blk, 0, stream>>>(
      row_ptr, csr, (const uint32_t*)xb_q, nullptr, nullptr,
      (uint32_t*)hb1, nullptr, kA[0], kB[0]);
  spmm_layer_kernel<1><<<grid, blk, 0, stream>>>(
      row_ptr, csr, (const uint32_t*)hb1, nullptr, nullptr,
      (uint32_t*)hb2, nullptr, kA[1], kB[1]);
  spmm_layer_kernel<2><<<grid, blk, 0, stream>>>(
      row_ptr, csr, (const uint32_t*)hb2, (const uint32_t*)xb_q,
      (const uint32_t*)hb1, nullptr, (float2*)out, kA[2], kB[2]);
}